// Round 7
// baseline (366.204 us; speedup 1.0000x reference)
//
#include <hip/hip_runtime.h>
#include <math.h>

// B=8, L=512, H=768, T=9, HEADS=12, d=64
//   Q = hs@Wq + bq ; K = hs@Wk + bk  (M=4096, N=6912, K=768)  -> RoPE -> bf16
//   score[b,i,j,t] = (1/96) * Qr[b*512+i, t*768:+768] . Kr[b*512+j, t*768:+768]
// R6: LDS-BW was the binding constraint (reads+DMA ~1.65x MFMA cycles at 64x64
// wave-tiles). Fix: B operand loaded DIRECTLY global->VGPR as MFMA fragments
// (16 fully-consumed lines per dwordx4 across the wave); only A staged in LDS
// (R5-proven layout/swizzle). LDS/block 32KB -> 4-5 blocks/CU. Counted
// vmcnt(12) keeps next tile's 12 loads in flight across raw barriers.

typedef __attribute__((ext_vector_type(4))) float f32x4;
typedef __attribute__((ext_vector_type(8))) __bf16 bf16x8;
typedef __attribute__((ext_vector_type(8))) unsigned short ushort8;

#define HH   768
#define NCOL 6912
#define LL   512
#define NT   12      // K-tiles of 64

static __device__ __forceinline__ unsigned short f2bf(float f) {
  unsigned int u = __float_as_uint(f);
  u += 0x7FFFu + ((u >> 16) & 1u);
  return (unsigned short)(u >> 16);
}

static __device__ __forceinline__ void async16(const void* g, void* l) {
  __builtin_amdgcn_global_load_lds(
      (const __attribute__((address_space(1))) unsigned int*)g,
      (__attribute__((address_space(3))) unsigned int*)l, 16, 0, 0);
}

// ---------------- prep kernels ----------------

__global__ void k_conv_hs(const float4* __restrict__ in, ushort8* __restrict__ out) {
  int idx = blockIdx.x * 256 + threadIdx.x;
  float4 a = in[idx * 2], b = in[idx * 2 + 1];
  ushort8 o;
  o[0] = f2bf(a.x); o[1] = f2bf(a.y); o[2] = f2bf(a.z); o[3] = f2bf(a.w);
  o[4] = f2bf(b.x); o[5] = f2bf(b.y); o[6] = f2bf(b.z); o[7] = f2bf(b.w);
  out[idx] = o;
}

// W (768 x 6912) f32 -> Wt (6912 x 768) bf16, rows permuted for in-reg RoPE.
__global__ void k_transpose(const float* __restrict__ Wq, const float* __restrict__ Wk,
                            unsigned short* __restrict__ Wtq, unsigned short* __restrict__ Wtk) {
  __shared__ float tile[32][33];
  const float* W = blockIdx.z ? Wk : Wq;
  unsigned short* Wt = blockIdx.z ? Wtk : Wtq;
  int n0 = blockIdx.x * 32, k0 = blockIdx.y * 32;
  int tx = threadIdx.x, ty0 = threadIdx.y;
#pragma unroll
  for (int j = 0; j < 4; ++j) {
    int ty = ty0 + j * 8;
    tile[ty][tx] = W[(size_t)(k0 + ty) * NCOL + n0 + tx];
  }
  __syncthreads();
#pragma unroll
  for (int j = 0; j < 4; ++j) {
    int ty = ty0 + j * 8;
    int n = n0 + ty;
    int c = n & 63;
    int gc = ((c & 1) << 4) | ((c >> 5) << 5) | ((c & 31) >> 1);
    int np = (n & ~63) | gc;
    Wt[(size_t)np * HH + k0 + tx] = f2bf(tile[tx][ty]);
  }
}

__global__ void k_tables(float2* __restrict__ sc) {
  int idx = blockIdx.x * 256 + threadIdx.x;     // 16384
  int i = idx >> 5, p = idx & 31;
  double ang = (double)i * pow(10000.0, -(double)p / 32.0);
  sc[idx] = make_float2((float)sin(ang), (float)cos(ang));
}

// ------------- 128x128 BK=64 loop: A in LDS (dbuf), B direct-to-regs -------------
// A buffer 16KB: row r (128B stride), chunk c stored at c^(r&7) (0 conflicts, R5).
// Per tile per wave: 4 async16 (A) + 8 global_load_dwordx4 (B) + 8 ds_read_b128.
// vmcnt(12) retires tile t's A-DMA(4)+B(8), leaves t+1's 12 in flight.

template <int STRA, int STRB>
static __device__ __forceinline__ void k2_loop(
    const unsigned short* __restrict__ aSrc,   // per-lane pre-swizzled A stage src
    const unsigned short* __restrict__ bLane,  // per-lane B fragment base
    char* smem, int tid, f32x4 acc[4][4]) {
  const int lane = tid & 63, wid = tid >> 6;
  const int wr = wid >> 1;
  const int ldsW = wid * 1024;
  const int aRdBase = (wr * 64 + (lane & 15)) * 128;
  const int aci0 = ((lane >> 4) ^ (lane & 7)) << 4;
  const int aci1 = ((4 + (lane >> 4)) ^ (lane & 7)) << 4;

  auto stageA = [&](int bb, int kt) {
#pragma unroll
    for (int j = 0; j < 4; ++j)
      async16(aSrc + (size_t)(j * 32) * STRA + kt * 64,
              smem + bb * 16384 + j * 4096 + ldsW);
  };

  bf16x8 Ba[4][2], Bb[4][2];
  auto loadB = [&](bf16x8 (&Bd)[4][2], int kt) {
#pragma unroll
    for (int nf = 0; nf < 4; ++nf)
#pragma unroll
      for (int kk = 0; kk < 2; ++kk)
        Bd[nf][kk] = *(const bf16x8*)(bLane + (size_t)(nf * 16) * STRB + kt * 64 + kk * 32);
  };

  // prologue: A(0) DMA + B(0) regs  -> 12 outstanding
  stageA(0, 0);
  loadB(Ba, 0);

#define STEP(T, Buse, Bnxt) do { \
    const int kn = ((T) + 1 < NT) ? (T) + 1 : NT - 1; \
    stageA(((T) + 1) & 1, kn); \
    loadB(Bnxt, kn); \
    asm volatile("s_waitcnt vmcnt(12)" ::: "memory"); \
    __builtin_amdgcn_s_barrier(); \
    char* AB = smem + ((T) & 1) * 16384; \
    bf16x8 Af[4][2]; \
    _Pragma("unroll") for (int mf = 0; mf < 4; ++mf) { \
      Af[mf][0] = *(const bf16x8*)(AB + aRdBase + mf * 2048 + aci0); \
      Af[mf][1] = *(const bf16x8*)(AB + aRdBase + mf * 2048 + aci1); \
    } \
    _Pragma("unroll") for (int kk = 0; kk < 2; ++kk) \
    _Pragma("unroll") for (int mf = 0; mf < 4; ++mf) \
    _Pragma("unroll") for (int nf = 0; nf < 4; ++nf) \
      acc[mf][nf] = __builtin_amdgcn_mfma_f32_16x16x32_bf16( \
          Af[mf][kk], Buse[nf][kk], acc[mf][nf], 0, 0, 0); \
    __builtin_amdgcn_s_barrier(); \
  } while (0)

  for (int t = 0; t < NT; t += 2) {
    STEP(t, Ba, Bb);
    STEP(t + 1, Bb, Ba);
  }
#undef STEP
}

// ---------------- GEMM1: projection + bias + RoPE -> bf16 ----------------

__global__ __launch_bounds__(256) void k2_rope(
    const unsigned short* __restrict__ hsb,
    const unsigned short* __restrict__ Wtq, const unsigned short* __restrict__ Wtk,
    const float* __restrict__ bq, const float* __restrict__ bk,
    const float2* __restrict__ sc,
    unsigned short* __restrict__ Qr, unsigned short* __restrict__ Kr) {
  __shared__ __align__(16) char smem[32768];
  const int bid = blockIdx.x;                 // 3456 = 54n * 32m * 2z
  const int swz = (bid & 7) * 432 + (bid >> 3);
  const int ntile = swz % 54;
  const int rest = swz / 54;
  const int mtile = rest & 31, zz = rest >> 5;
  const unsigned short* Wt = zz ? Wtk : Wtq;
  const float* bias = zz ? bk : bq;
  unsigned short* outp = zz ? Kr : Qr;
  const int m0 = mtile * 128, n0 = ntile * 128;
  const int tid = threadIdx.x;
  const int lane = tid & 63, wid = tid >> 6;
  const int wr = wid >> 1, wc = wid & 1;

  const int row_in = tid >> 3;                // 0..31
  const int ci_u = (tid & 7) ^ (row_in & 7);  // pre-swizzled chunk
  const unsigned short* aSrc = hsb + (size_t)(m0 + row_in) * HH + ci_u * 8;
  const unsigned short* bLane = Wt + (size_t)(n0 + wc * 64 + (lane & 15)) * HH + (lane >> 4) * 8;

  f32x4 acc[4][4] = {};
  k2_loop<HH, HH>(aSrc, bLane, smem, tid, acc);

  const int cA = n0 + wc * 64;
  const int e0 = lane & 15, e1 = 16 + e0;
  const float b1a = bias[cA + 2 * e0], b2a = bias[cA + 2 * e0 + 1];
  const float b1b = bias[cA + 2 * e1], b2b = bias[cA + 2 * e1 + 1];

#pragma unroll
  for (int mf = 0; mf < 4; ++mf) {
    const int rbase = m0 + wr * 64 + mf * 16 + (lane >> 4) * 4;
#pragma unroll
    for (int q = 0; q < 4; ++q) {
      const int grow = rbase + q;
      const int i = grow & (LL - 1);
      float2 s0 = sc[i * 32 + e0];
      float2 s1 = sc[i * 32 + e1];
      float x1 = acc[mf][0][q] + b1a, x2 = acc[mf][1][q] + b2a;
      float y1 = acc[mf][2][q] + b1b, y2 = acc[mf][3][q] + b2b;
      size_t ro = (size_t)grow * NCOL + cA;
      outp[ro + e0]      = f2bf(x1 * s0.y - x2 * s0.x);
      outp[ro + e0 + 32] = f2bf(x2 * s0.y + x1 * s0.x);
      outp[ro + e1]      = f2bf(y1 * s1.y - y2 * s1.x);
      outp[ro + e1 + 32] = f2bf(y2 * s1.y + y1 * s1.x);
    }
  }
}

// ---------------- GEMM2: score ----------------

__global__ __launch_bounds__(256) void k2_score(
    const unsigned short* __restrict__ Qr, const unsigned short* __restrict__ Kr,
    float* __restrict__ out) {
  __shared__ __align__(16) char smem[32768];
  const int bid = blockIdx.x;                 // 1152 = 9t * 4jt * 4it * 8b
  const int swz = (bid & 7) * 144 + (bid >> 3);
  const int t = swz % 9;
  const int r2 = swz / 9;
  const int jt = r2 & 3, it = (r2 >> 2) & 3, b = r2 >> 4;
  const int tid = threadIdx.x;
  const int lane = tid & 63, wid = tid >> 6;
  const int wr = wid >> 1, wc = wid & 1;

  const int row_in = tid >> 3;
  const int ci_u = (tid & 7) ^ (row_in & 7);
  const unsigned short* aSrc = Qr + (size_t)(b * 512 + it * 128 + row_in) * NCOL + t * HH + ci_u * 8;
  const unsigned short* bLane = Kr + (size_t)(b * 512 + jt * 128 + wc * 64 + (lane & 15)) * NCOL
                                + t * HH + (lane >> 4) * 8;

  f32x4 acc[4][4] = {};
  k2_loop<NCOL, NCOL>(aSrc, bLane, smem, tid, acc);

  const float SC = 0.125f / 12.0f;   // 64^-0.5 / 12
#pragma unroll
  for (int mf = 0; mf < 4; ++mf) {
    const int i0 = it * 128 + wr * 64 + mf * 16 + (lane >> 4) * 4;
#pragma unroll
    for (int nf = 0; nf < 4; ++nf) {
      const int j = jt * 128 + wc * 64 + nf * 16 + (lane & 15);
#pragma unroll
      for (int q = 0; q < 4; ++q) {
        size_t o = ((size_t)(b * 512 + i0 + q) * 512 + j) * 9 + t;
        out[o] = acc[mf][nf][q] * SC;
      }
    }
  }
}

// ---------------- launch ----------------

extern "C" void kernel_launch(void* const* d_in, const int* in_sizes, int n_in,
                              void* d_out, int out_size, void* d_ws, size_t ws_size,
                              hipStream_t stream) {
  const float* hs = (const float*)d_in[0];
  const float* Wq = (const float*)d_in[1];
  const float* bq = (const float*)d_in[2];
  const float* Wk = (const float*)d_in[3];
  const float* bk = (const float*)d_in[4];
  float* out = (float*)d_out;
  char* ws = (char*)d_ws;

  float2* sctab = (float2*)(ws);                               //  131072
  unsigned short* hsb = (unsigned short*)(ws + 131072);        // 6291456
  unsigned short* Wtq = (unsigned short*)(ws + 6422528);       // 10616832
  unsigned short* Wtk = (unsigned short*)(ws + 17039360);      // 10616832
  unsigned short* Qr  = (unsigned short*)(ws + 27656192);      // 56623104
  unsigned short* Kr  = (unsigned short*)(ws + 84279296);      // 56623104 -> 140902400

  hipLaunchKernelGGL(k_conv_hs, dim3(1536), dim3(256), 0, stream,
                     (const float4*)hs, (ushort8*)hsb);
  hipLaunchKernelGGL(k_transpose, dim3(216, 24, 2), dim3(32, 8), 0, stream,
                     Wq, Wk, Wtq, Wtk);
  hipLaunchKernelGGL(k_tables, dim3(64), dim3(256), 0, stream, sctab);
  hipLaunchKernelGGL(k2_rope, dim3(3456), dim3(256), 0, stream,
                     hsb, Wtq, Wtk, bq, bk, sctab, Qr, Kr);
  hipLaunchKernelGGL(k2_score, dim3(1152), dim3(256), 0, stream, Qr, Kr, out);
}

// Round 8
// 256.129 us; speedup vs baseline: 1.4298x; 1.4298x over previous
//
#include <hip/hip_runtime.h>
#include <math.h>

// B=8, L=512, H=768, T=9, HEADS=12, d=64
//   Q = hs@Wq + bq ; K = hs@Wk + bk  (M=4096, N=6912, K=768)  -> RoPE -> bf16
//   score[b,i,j,t] = (1/96) * Qr[b*512+i, t*768:+768] . Kr[b*512+j, t*768:+768]
// R7: R5's 128x128 BK=64 dbuf counted-vmcnt engine (reverted from R6's
// direct-B regression) + L2-aware supertiled block ordering:
//   rope: per-XCD 8m x 6n supertiles (working set ~2.7MB < 4MB L2)
//   score: XCD = batch (write-merge in one L2), t-outer 4x4 (it,jt) inner.

typedef __attribute__((ext_vector_type(4))) float f32x4;
typedef __attribute__((ext_vector_type(8))) __bf16 bf16x8;
typedef __attribute__((ext_vector_type(8))) unsigned short ushort8;

#define HH   768
#define NCOL 6912
#define LL   512
#define NT   12      // K-tiles of 64

static __device__ __forceinline__ unsigned short f2bf(float f) {
  unsigned int u = __float_as_uint(f);
  u += 0x7FFFu + ((u >> 16) & 1u);
  return (unsigned short)(u >> 16);
}

static __device__ __forceinline__ void async16(const void* g, void* l) {
  __builtin_amdgcn_global_load_lds(
      (const __attribute__((address_space(1))) unsigned int*)g,
      (__attribute__((address_space(3))) unsigned int*)l, 16, 0, 0);
}

// ---------------- prep kernels ----------------

__global__ void k_conv_hs(const float4* __restrict__ in, ushort8* __restrict__ out) {
  int idx = blockIdx.x * 256 + threadIdx.x;
  float4 a = in[idx * 2], b = in[idx * 2 + 1];
  ushort8 o;
  o[0] = f2bf(a.x); o[1] = f2bf(a.y); o[2] = f2bf(a.z); o[3] = f2bf(a.w);
  o[4] = f2bf(b.x); o[5] = f2bf(b.y); o[6] = f2bf(b.z); o[7] = f2bf(b.w);
  out[idx] = o;
}

// W (768 x 6912) f32 -> Wt (6912 x 768) bf16, rows permuted for in-reg RoPE.
__global__ void k_transpose(const float* __restrict__ Wq, const float* __restrict__ Wk,
                            unsigned short* __restrict__ Wtq, unsigned short* __restrict__ Wtk) {
  __shared__ float tile[32][33];
  const float* W = blockIdx.z ? Wk : Wq;
  unsigned short* Wt = blockIdx.z ? Wtk : Wtq;
  int n0 = blockIdx.x * 32, k0 = blockIdx.y * 32;
  int tx = threadIdx.x, ty0 = threadIdx.y;
#pragma unroll
  for (int j = 0; j < 4; ++j) {
    int ty = ty0 + j * 8;
    tile[ty][tx] = W[(size_t)(k0 + ty) * NCOL + n0 + tx];
  }
  __syncthreads();
#pragma unroll
  for (int j = 0; j < 4; ++j) {
    int ty = ty0 + j * 8;
    int n = n0 + ty;
    int c = n & 63;
    int gc = ((c & 1) << 4) | ((c >> 5) << 5) | ((c & 31) >> 1);
    int np = (n & ~63) | gc;
    Wt[(size_t)np * HH + k0 + tx] = f2bf(tile[tx][ty]);
  }
}

__global__ void k_tables(float2* __restrict__ sc) {
  int idx = blockIdx.x * 256 + threadIdx.x;     // 16384
  int i = idx >> 5, p = idx & 31;
  double ang = (double)i * pow(10000.0, -(double)p / 32.0);
  sc[idx] = make_float2((float)sin(ang), (float)cos(ang));
}

// ---------------- 128x128 BK=64 dbuf counted-vmcnt 2-phase K-loop ----------------
// LDS buf (32KB): A[128 rows][64 K] at byte r*128 + (chunk^(r&7))*16, B same +16K.
// Per tile: STAGE(nxt,t+1) 8 loads; vmcnt(8); barrier; 16 ds_read + 32 MFMA; barrier.

template <int STR>
static __device__ __forceinline__ void k2_loop(
    const unsigned short* __restrict__ aSrc, const unsigned short* __restrict__ bSrc,
    char* smem, int tid, f32x4 acc[4][4]) {
  const int lane = tid & 63, wid = tid >> 6;
  const int wr = wid >> 1, wc = wid & 1;
  const int ldsW = wid * 1024;
  const int aRdBase = (wr * 64 + (lane & 15)) * 128;
  const int bRdBase = (wc * 64 + (lane & 15)) * 128;
  const int aci0 = ((lane >> 4) ^ (lane & 7)) << 4;
  const int aci1 = ((4 + (lane >> 4)) ^ (lane & 7)) << 4;

  auto stage = [&](int bb, int kt) {
#pragma unroll
    for (int j = 0; j < 4; ++j) {
      async16(aSrc + (size_t)(j * 32) * STR + kt * 64,
              smem + bb * 32768 + j * 4096 + ldsW);
      async16(bSrc + (size_t)(j * 32) * STR + kt * 64,
              smem + bb * 32768 + 16384 + j * 4096 + ldsW);
    }
  };

  stage(0, 0);          // prologue: tile 0 (8 loads in flight)
  int cur = 0;
  for (int t = 0; t < NT; ++t) {
    const int ktn = (t + 1 < NT) ? t + 1 : NT - 1;   // clamped: keeps count exact
    stage(cur ^ 1, ktn);                              // 8 more loads
    asm volatile("s_waitcnt vmcnt(8)" ::: "memory");  // tile t landed; t+1 in flight
    __builtin_amdgcn_s_barrier();

    char* AB = smem + cur * 32768;
    char* BB = AB + 16384;
    bf16x8 Af[4][2], Bf[4][2];
#pragma unroll
    for (int mf = 0; mf < 4; ++mf) {
      Af[mf][0] = *(const bf16x8*)(AB + aRdBase + mf * 2048 + aci0);
      Af[mf][1] = *(const bf16x8*)(AB + aRdBase + mf * 2048 + aci1);
    }
#pragma unroll
    for (int nf = 0; nf < 4; ++nf) {
      Bf[nf][0] = *(const bf16x8*)(BB + bRdBase + nf * 2048 + aci0);
      Bf[nf][1] = *(const bf16x8*)(BB + bRdBase + nf * 2048 + aci1);
    }
#pragma unroll
    for (int kk = 0; kk < 2; ++kk)
#pragma unroll
      for (int mf = 0; mf < 4; ++mf)
#pragma unroll
        for (int nf = 0; nf < 4; ++nf)
          acc[mf][nf] = __builtin_amdgcn_mfma_f32_16x16x32_bf16(
              Af[mf][kk], Bf[nf][kk], acc[mf][nf], 0, 0, 0);
    __builtin_amdgcn_s_barrier();   // all reads of buf[cur] done -> writable next iter
    cur ^= 1;
  }
}

// ---------------- GEMM1: projection + bias + RoPE -> bf16 ----------------

__global__ __launch_bounds__(256) void k2_rope(
    const unsigned short* __restrict__ hsb,
    const unsigned short* __restrict__ Wtq, const unsigned short* __restrict__ Wtk,
    const float* __restrict__ bq, const float* __restrict__ bk,
    const float2* __restrict__ sc,
    unsigned short* __restrict__ Qr, unsigned short* __restrict__ Kr) {
  __shared__ __align__(16) char smem[65536];
  // L2-aware decode: grid 3456; xcd = bid&7 gets supertiles xcd*9..xcd*9+8.
  // Supertile = 8m x 6n (48 blocks, ~2.7MB panel set). 72 supertiles = 2z*4mr*9nc.
  const int bid = blockIdx.x;
  const int xcd = bid & 7, idx = bid >> 3;        // idx 0..431
  const int st = xcd * 9 + idx / 48;              // 0..71
  const int u = idx % 48;
  const int dm = u & 7, dn = u >> 3;              // 8m x 6n, m fastest
  const int z = st / 36, r = st % 36;
  const int smr = r & 3, snc = r >> 2;            // 4 x 9
  const int mtile = smr * 8 + dm;                 // 0..31
  const int ntile = snc * 6 + dn;                 // 0..53
  const unsigned short* Wt = z ? Wtk : Wtq;
  const float* bias = z ? bk : bq;
  unsigned short* outp = z ? Kr : Qr;
  const int m0 = mtile * 128, n0 = ntile * 128;
  const int tid = threadIdx.x;
  const int lane = tid & 63, wid = tid >> 6;
  const int wr = wid >> 1, wc = wid & 1;

  const int row_in = tid >> 3;                // 0..31
  const int ci_u = (tid & 7) ^ (row_in & 7);  // pre-swizzled chunk
  const unsigned short* aSrc = hsb + (size_t)(m0 + row_in) * HH + ci_u * 8;
  const unsigned short* bSrc = Wt + (size_t)(n0 + row_in) * HH + ci_u * 8;

  f32x4 acc[4][4] = {};
  k2_loop<HH>(aSrc, bSrc, smem, tid, acc);

  const int cA = n0 + wc * 64;
  const int e0 = lane & 15, e1 = 16 + e0;
  const float b1a = bias[cA + 2 * e0], b2a = bias[cA + 2 * e0 + 1];
  const float b1b = bias[cA + 2 * e1], b2b = bias[cA + 2 * e1 + 1];

#pragma unroll
  for (int mf = 0; mf < 4; ++mf) {
    const int rbase = m0 + wr * 64 + mf * 16 + (lane >> 4) * 4;
#pragma unroll
    for (int q = 0; q < 4; ++q) {
      const int grow = rbase + q;
      const int i = grow & (LL - 1);
      float2 s0 = sc[i * 32 + e0];
      float2 s1 = sc[i * 32 + e1];
      float x1 = acc[mf][0][q] + b1a, x2 = acc[mf][1][q] + b2a;
      float y1 = acc[mf][2][q] + b1b, y2 = acc[mf][3][q] + b2b;
      size_t ro = (size_t)grow * NCOL + cA;
      outp[ro + e0]      = f2bf(x1 * s0.y - x2 * s0.x);
      outp[ro + e0 + 32] = f2bf(x2 * s0.y + x1 * s0.x);
      outp[ro + e1]      = f2bf(y1 * s1.y - y2 * s1.x);
      outp[ro + e1 + 32] = f2bf(y2 * s1.y + y1 * s1.x);
    }
  }
}

// ---------------- GEMM2: score ----------------

__global__ __launch_bounds__(256) void k2_score(
    const unsigned short* __restrict__ Qr, const unsigned short* __restrict__ Kr,
    float* __restrict__ out) {
  __shared__ __align__(16) char smem[65536];
  // XCD = batch: all writes to out[b] merge in one L2. t-outer, 4x4 (it,jt) inner.
  const int bid = blockIdx.x;
  const int b = bid & 7, idx = bid >> 3;          // idx 0..143
  const int t = idx >> 4;                         // 0..8 (slow)
  const int p = idx & 15;
  const int it = p >> 2, jt = p & 3;
  const int tid = threadIdx.x;
  const int lane = tid & 63, wid = tid >> 6;
  const int wr = wid >> 1, wc = wid & 1;

  const int row_in = tid >> 3;
  const int ci_u = (tid & 7) ^ (row_in & 7);
  const unsigned short* aSrc = Qr + (size_t)(b * 512 + it * 128 + row_in) * NCOL + t * HH + ci_u * 8;
  const unsigned short* bSrc = Kr + (size_t)(b * 512 + jt * 128 + row_in) * NCOL + t * HH + ci_u * 8;

  f32x4 acc[4][4] = {};
  k2_loop<NCOL>(aSrc, bSrc, smem, tid, acc);

  const float SC = 0.125f / 12.0f;   // 64^-0.5 / 12
#pragma unroll
  for (int mf = 0; mf < 4; ++mf) {
    const int i0 = it * 128 + wr * 64 + mf * 16 + (lane >> 4) * 4;
#pragma unroll
    for (int nf = 0; nf < 4; ++nf) {
      const int j = jt * 128 + wc * 64 + nf * 16 + (lane & 15);
#pragma unroll
      for (int q = 0; q < 4; ++q) {
        size_t o = ((size_t)(b * 512 + i0 + q) * 512 + j) * 9 + t;
        out[o] = acc[mf][nf][q] * SC;
      }
    }
  }
}

// ---------------- launch ----------------

extern "C" void kernel_launch(void* const* d_in, const int* in_sizes, int n_in,
                              void* d_out, int out_size, void* d_ws, size_t ws_size,
                              hipStream_t stream) {
  const float* hs = (const float*)d_in[0];
  const float* Wq = (const float*)d_in[1];
  const float* bq = (const float*)d_in[2];
  const float* Wk = (const float*)d_in[3];
  const float* bk = (const float*)d_in[4];
  float* out = (float*)d_out;
  char* ws = (char*)d_ws;

  float2* sctab = (float2*)(ws);                               //  131072
  unsigned short* hsb = (unsigned short*)(ws + 131072);        // 6291456
  unsigned short* Wtq = (unsigned short*)(ws + 6422528);       // 10616832
  unsigned short* Wtk = (unsigned short*)(ws + 17039360);      // 10616832
  unsigned short* Qr  = (unsigned short*)(ws + 27656192);      // 56623104
  unsigned short* Kr  = (unsigned short*)(ws + 84279296);      // 56623104 -> 140902400

  hipLaunchKernelGGL(k_conv_hs, dim3(1536), dim3(256), 0, stream,
                     (const float4*)hs, (ushort8*)hsb);
  hipLaunchKernelGGL(k_transpose, dim3(216, 24, 2), dim3(32, 8), 0, stream,
                     Wq, Wk, Wtq, Wtk);
  hipLaunchKernelGGL(k_tables, dim3(64), dim3(256), 0, stream, sctab);
  hipLaunchKernelGGL(k2_rope, dim3(3456), dim3(256), 0, stream,
                     hsb, Wtq, Wtk, bq, bk, sctab, Qr, Kr);
  hipLaunchKernelGGL(k2_score, dim3(1152), dim3(256), 0, stream, Qr, Kr, out);
}

// Round 9
// 192.307 us; speedup vs baseline: 1.9043x; 1.3319x over previous
//
#include <hip/hip_runtime.h>
#include <math.h>

// B=8, L=512, H=768, T=9, HEADS=12, d=64
//   Q = hs@Wq + bq ; K = hs@Wk + bk  (M=4096, N=6912, K=768)  -> RoPE -> bf16
//   score[b,i,j,t] = (1/96) * Qr[b*512+i, t*768:+768] . Kr[b*512+j, t*768:+768]
// R8: score rewritten t-FUSED: block = (b,it,jt) 64x64 tile, all 9 t
// accumulated in registers over one flat 108-tile K-pipeline (c = t*768+k is
// linear), epilogue writes each (i,j)'s 9 floats contiguously -> kills the
// 5.8x write amplification R7 exposed (437MB -> ~80MB). rope unchanged.

typedef __attribute__((ext_vector_type(4))) float f32x4;
typedef __attribute__((ext_vector_type(8))) __bf16 bf16x8;
typedef __attribute__((ext_vector_type(8))) unsigned short ushort8;

#define HH   768
#define NCOL 6912
#define LL   512
#define NT   12      // K-tiles of 64 per t (rope); score uses 9*12 = 108 flat

static __device__ __forceinline__ unsigned short f2bf(float f) {
  unsigned int u = __float_as_uint(f);
  u += 0x7FFFu + ((u >> 16) & 1u);
  return (unsigned short)(u >> 16);
}

static __device__ __forceinline__ void async16(const void* g, void* l) {
  __builtin_amdgcn_global_load_lds(
      (const __attribute__((address_space(1))) unsigned int*)g,
      (__attribute__((address_space(3))) unsigned int*)l, 16, 0, 0);
}

// ---------------- prep kernels ----------------

__global__ void k_conv_hs(const float4* __restrict__ in, ushort8* __restrict__ out) {
  int idx = blockIdx.x * 256 + threadIdx.x;
  float4 a = in[idx * 2], b = in[idx * 2 + 1];
  ushort8 o;
  o[0] = f2bf(a.x); o[1] = f2bf(a.y); o[2] = f2bf(a.z); o[3] = f2bf(a.w);
  o[4] = f2bf(b.x); o[5] = f2bf(b.y); o[6] = f2bf(b.z); o[7] = f2bf(b.w);
  out[idx] = o;
}

// W (768 x 6912) f32 -> Wt (6912 x 768) bf16, rows permuted for in-reg RoPE.
__global__ void k_transpose(const float* __restrict__ Wq, const float* __restrict__ Wk,
                            unsigned short* __restrict__ Wtq, unsigned short* __restrict__ Wtk) {
  __shared__ float tile[32][33];
  const float* W = blockIdx.z ? Wk : Wq;
  unsigned short* Wt = blockIdx.z ? Wtk : Wtq;
  int n0 = blockIdx.x * 32, k0 = blockIdx.y * 32;
  int tx = threadIdx.x, ty0 = threadIdx.y;
#pragma unroll
  for (int j = 0; j < 4; ++j) {
    int ty = ty0 + j * 8;
    tile[ty][tx] = W[(size_t)(k0 + ty) * NCOL + n0 + tx];
  }
  __syncthreads();
#pragma unroll
  for (int j = 0; j < 4; ++j) {
    int ty = ty0 + j * 8;
    int n = n0 + ty;
    int c = n & 63;
    int gc = ((c & 1) << 4) | ((c >> 5) << 5) | ((c & 31) >> 1);
    int np = (n & ~63) | gc;
    Wt[(size_t)np * HH + k0 + tx] = f2bf(tile[tx][ty]);
  }
}

__global__ void k_tables(float2* __restrict__ sc) {
  int idx = blockIdx.x * 256 + threadIdx.x;     // 16384
  int i = idx >> 5, p = idx & 31;
  double ang = (double)i * pow(10000.0, -(double)p / 32.0);
  sc[idx] = make_float2((float)sin(ang), (float)cos(ang));
}

// ---------------- 128x128 BK=64 dbuf counted-vmcnt engine (rope) ----------------

template <int STR>
static __device__ __forceinline__ void k2_loop(
    const unsigned short* __restrict__ aSrc, const unsigned short* __restrict__ bSrc,
    char* smem, int tid, f32x4 acc[4][4]) {
  const int lane = tid & 63, wid = tid >> 6;
  const int wr = wid >> 1, wc = wid & 1;
  const int ldsW = wid * 1024;
  const int aRdBase = (wr * 64 + (lane & 15)) * 128;
  const int bRdBase = (wc * 64 + (lane & 15)) * 128;
  const int aci0 = ((lane >> 4) ^ (lane & 7)) << 4;
  const int aci1 = ((4 + (lane >> 4)) ^ (lane & 7)) << 4;

  auto stage = [&](int bb, int kt) {
#pragma unroll
    for (int j = 0; j < 4; ++j) {
      async16(aSrc + (size_t)(j * 32) * STR + kt * 64,
              smem + bb * 32768 + j * 4096 + ldsW);
      async16(bSrc + (size_t)(j * 32) * STR + kt * 64,
              smem + bb * 32768 + 16384 + j * 4096 + ldsW);
    }
  };

  stage(0, 0);
  int cur = 0;
  for (int t = 0; t < NT; ++t) {
    const int ktn = (t + 1 < NT) ? t + 1 : NT - 1;
    stage(cur ^ 1, ktn);
    asm volatile("s_waitcnt vmcnt(8)" ::: "memory");
    __builtin_amdgcn_s_barrier();

    char* AB = smem + cur * 32768;
    char* BB = AB + 16384;
    bf16x8 Af[4][2], Bf[4][2];
#pragma unroll
    for (int mf = 0; mf < 4; ++mf) {
      Af[mf][0] = *(const bf16x8*)(AB + aRdBase + mf * 2048 + aci0);
      Af[mf][1] = *(const bf16x8*)(AB + aRdBase + mf * 2048 + aci1);
    }
#pragma unroll
    for (int nf = 0; nf < 4; ++nf) {
      Bf[nf][0] = *(const bf16x8*)(BB + bRdBase + nf * 2048 + aci0);
      Bf[nf][1] = *(const bf16x8*)(BB + bRdBase + nf * 2048 + aci1);
    }
#pragma unroll
    for (int kk = 0; kk < 2; ++kk)
#pragma unroll
      for (int mf = 0; mf < 4; ++mf)
#pragma unroll
        for (int nf = 0; nf < 4; ++nf)
          acc[mf][nf] = __builtin_amdgcn_mfma_f32_16x16x32_bf16(
              Af[mf][kk], Bf[nf][kk], acc[mf][nf], 0, 0, 0);
    __builtin_amdgcn_s_barrier();
    cur ^= 1;
  }
}

// ---------------- GEMM1: projection + bias + RoPE -> bf16 (R7 verbatim) ----------------

__global__ __launch_bounds__(256) void k2_rope(
    const unsigned short* __restrict__ hsb,
    const unsigned short* __restrict__ Wtq, const unsigned short* __restrict__ Wtk,
    const float* __restrict__ bq, const float* __restrict__ bk,
    const float2* __restrict__ sc,
    unsigned short* __restrict__ Qr, unsigned short* __restrict__ Kr) {
  __shared__ __align__(16) char smem[65536];
  const int bid = blockIdx.x;
  const int xcd = bid & 7, idx = bid >> 3;
  const int st = xcd * 9 + idx / 48;
  const int u = idx % 48;
  const int dm = u & 7, dn = u >> 3;
  const int z = st / 36, r = st % 36;
  const int smr = r & 3, snc = r >> 2;
  const int mtile = smr * 8 + dm;
  const int ntile = snc * 6 + dn;
  const unsigned short* Wt = z ? Wtk : Wtq;
  const float* bias = z ? bk : bq;
  unsigned short* outp = z ? Kr : Qr;
  const int m0 = mtile * 128, n0 = ntile * 128;
  const int tid = threadIdx.x;
  const int lane = tid & 63, wid = tid >> 6;
  const int wr = wid >> 1, wc = wid & 1;

  const int row_in = tid >> 3;
  const int ci_u = (tid & 7) ^ (row_in & 7);
  const unsigned short* aSrc = hsb + (size_t)(m0 + row_in) * HH + ci_u * 8;
  const unsigned short* bSrc = Wt + (size_t)(n0 + row_in) * HH + ci_u * 8;

  f32x4 acc[4][4] = {};
  k2_loop<HH>(aSrc, bSrc, smem, tid, acc);

  const int cA = n0 + wc * 64;
  const int e0 = lane & 15, e1 = 16 + e0;
  const float b1a = bias[cA + 2 * e0], b2a = bias[cA + 2 * e0 + 1];
  const float b1b = bias[cA + 2 * e1], b2b = bias[cA + 2 * e1 + 1];

#pragma unroll
  for (int mf = 0; mf < 4; ++mf) {
    const int rbase = m0 + wr * 64 + mf * 16 + (lane >> 4) * 4;
#pragma unroll
    for (int q = 0; q < 4; ++q) {
      const int grow = rbase + q;
      const int i = grow & (LL - 1);
      float2 s0 = sc[i * 32 + e0];
      float2 s1 = sc[i * 32 + e1];
      float x1 = acc[mf][0][q] + b1a, x2 = acc[mf][1][q] + b2a;
      float y1 = acc[mf][2][q] + b1b, y2 = acc[mf][3][q] + b2b;
      size_t ro = (size_t)grow * NCOL + cA;
      outp[ro + e0]      = f2bf(x1 * s0.y - x2 * s0.x);
      outp[ro + e0 + 32] = f2bf(x2 * s0.y + x1 * s0.x);
      outp[ro + e1]      = f2bf(y1 * s1.y - y2 * s1.x);
      outp[ro + e1 + 32] = f2bf(y2 * s1.y + y1 * s1.x);
    }
  }
}

// ---------------- GEMM2: score, t-FUSED 64x64 tile ----------------
// Block (b,it,jt): 9 accumulators (one per t), flat 108-tile K-pipeline over
// c=0..6911. LDS dbuf 2x16KB (A 8KB + B 8KB). Per wave per tile: 4 async16,
// vmcnt(4), 8 ds_read_b128, 8 MFMA. Epilogue: 9 contiguous floats per (i,j).

__global__ __launch_bounds__(256, 2) void k9_score(
    const unsigned short* __restrict__ Qr, const unsigned short* __restrict__ Kr,
    float* __restrict__ out) {
  __shared__ __align__(16) char smem[32768];
  const int bid = blockIdx.x;                 // 512 = 8b * 16s * 4q
  const int b = bid & 7, idx = bid >> 3;      // XCD = batch
  const int s = idx >> 2, q4 = idx & 3;       // 2x2 (it,jt) supertiles
  const int it = (s >> 2) * 2 + (q4 >> 1);    // 0..7
  const int jt = (s & 3) * 2 + (q4 & 1);      // 0..7
  const int tid = threadIdx.x;
  const int lane = tid & 63, wid = tid >> 6;
  const int wr = wid >> 1, wc = wid & 1;

  // staging: wave w pass p covers LDS bytes p*4096 + w*1024 (+lane*16)
  // -> row = p*32 + w*8 + (lane>>3), chunk c = (lane&7) ^ (lane>>3)
  const int srow = wid * 8 + (lane >> 3);
  const int sch = (lane & 7) ^ (lane >> 3);
  const unsigned short* aBase = Qr + (size_t)(b * 512 + it * 64 + srow) * NCOL + sch * 8;
  const unsigned short* bBase = Kr + (size_t)(b * 512 + jt * 64 + srow) * NCOL + sch * 8;

  auto stage = [&](int bb, int g) {
    const unsigned short* ga = aBase + g * 64;
    const unsigned short* gb = bBase + g * 64;
    char* l = smem + bb * 16384 + wid * 1024;
    async16(ga, l);
    async16(ga + (size_t)32 * NCOL, l + 4096);
    async16(gb, l + 8192);
    async16(gb + (size_t)32 * NCOL, l + 12288);
  };

  // ds_read addressing (16x16x32 frags, XOR-swizzled chunks)
  const int aR0 = (wr * 32 + (lane & 15)) * 128;   // A local row * 128B
  const int bR0 = (wc * 32 + (lane & 15)) * 128;
  const int ar7 = (wr * 32 + (lane & 15)) & 7;
  const int br7 = (wc * 32 + (lane & 15)) & 7;
  const int cc0 = lane >> 4;                        // kk=0 chunk base
  const int aci0 = ((cc0) ^ ar7) << 4, aci1 = ((4 + cc0) ^ ar7) << 4;
  const int bci0 = ((cc0) ^ br7) << 4, bci1 = ((4 + cc0) ^ br7) << 4;

  f32x4 acc[9][2][2] = {};

  stage(0, 0);
#pragma unroll
  for (int tt = 0; tt < 9; ++tt) {
    for (int kt = 0; kt < 12; ++kt) {
      const int g = tt * 12 + kt;
      const int cur = g & 1;
      if (g < 107) {
        stage(cur ^ 1, g + 1);
        asm volatile("s_waitcnt vmcnt(4)" ::: "memory");
      } else {
        asm volatile("s_waitcnt vmcnt(0)" ::: "memory");
      }
      __builtin_amdgcn_s_barrier();

      char* AB = smem + cur * 16384;
      char* BB = AB + 8192;
      bf16x8 Af[2][2], Bf[2][2];
#pragma unroll
      for (int mf = 0; mf < 2; ++mf) {
        Af[mf][0] = *(const bf16x8*)(AB + aR0 + mf * 2048 + aci0);
        Af[mf][1] = *(const bf16x8*)(AB + aR0 + mf * 2048 + aci1);
      }
#pragma unroll
      for (int nf = 0; nf < 2; ++nf) {
        Bf[nf][0] = *(const bf16x8*)(BB + bR0 + nf * 2048 + bci0);
        Bf[nf][1] = *(const bf16x8*)(BB + bR0 + nf * 2048 + bci1);
      }
#pragma unroll
      for (int kk = 0; kk < 2; ++kk)
#pragma unroll
        for (int mf = 0; mf < 2; ++mf)
#pragma unroll
          for (int nf = 0; nf < 2; ++nf)
            acc[tt][mf][nf] = __builtin_amdgcn_mfma_f32_16x16x32_bf16(
                Af[mf][kk], Bf[nf][kk], acc[tt][mf][nf], 0, 0, 0);
      __builtin_amdgcn_s_barrier();
    }
  }

  // epilogue: per (i,j) cell write 9 contiguous floats
  const float SC = 0.125f / 12.0f;   // 64^-0.5 / 12
#pragma unroll
  for (int mf = 0; mf < 2; ++mf)
#pragma unroll
    for (int q = 0; q < 4; ++q) {
      const int i = it * 64 + wr * 32 + mf * 16 + (lane >> 4) * 4 + q;
#pragma unroll
      for (int nf = 0; nf < 2; ++nf) {
        const int j = jt * 64 + wc * 32 + nf * 16 + (lane & 15);
        float* o = out + ((size_t)(b * 512 + i) * 512 + j) * 9;
#pragma unroll
        for (int t = 0; t < 9; ++t)
          o[t] = acc[t][mf][nf][q] * SC;
      }
    }
}

// ---------------- launch ----------------

extern "C" void kernel_launch(void* const* d_in, const int* in_sizes, int n_in,
                              void* d_out, int out_size, void* d_ws, size_t ws_size,
                              hipStream_t stream) {
  const float* hs = (const float*)d_in[0];
  const float* Wq = (const float*)d_in[1];
  const float* bq = (const float*)d_in[2];
  const float* Wk = (const float*)d_in[3];
  const float* bk = (const float*)d_in[4];
  float* out = (float*)d_out;
  char* ws = (char*)d_ws;

  float2* sctab = (float2*)(ws);                               //  131072
  unsigned short* hsb = (unsigned short*)(ws + 131072);        // 6291456
  unsigned short* Wtq = (unsigned short*)(ws + 6422528);       // 10616832
  unsigned short* Wtk = (unsigned short*)(ws + 17039360);      // 10616832
  unsigned short* Qr  = (unsigned short*)(ws + 27656192);      // 56623104
  unsigned short* Kr  = (unsigned short*)(ws + 84279296);      // 56623104 -> 140902400

  hipLaunchKernelGGL(k_conv_hs, dim3(1536), dim3(256), 0, stream,
                     (const float4*)hs, (ushort8*)hsb);
  hipLaunchKernelGGL(k_transpose, dim3(216, 24, 2), dim3(32, 8), 0, stream,
                     Wq, Wk, Wtq, Wtk);
  hipLaunchKernelGGL(k_tables, dim3(64), dim3(256), 0, stream, sctab);
  hipLaunchKernelGGL(k2_rope, dim3(3456), dim3(256), 0, stream,
                     hsb, Wtq, Wtk, bq, bk, sctab, Qr, Kr);
  hipLaunchKernelGGL(k9_score, dim3(512), dim3(256), 0, stream, Qr, Kr, out);
}